// Round 2
// baseline (1709.211 us; speedup 1.0000x reference)
//
#include <hip/hip_runtime.h>
#include <hip/hip_bf16.h>

#define D_MODEL 1024
#define HIDDEN  4096
#define NTOK    16384
#define HP      12288   // shared + expert0 + expert1 hidden, concatenated

typedef __hip_bfloat16 bf16;
typedef __attribute__((ext_vector_type(8))) short short8;
typedef __attribute__((ext_vector_type(4))) float floatx4;

struct bf16x4 { bf16 a, b, c, d; };

__device__ inline void gload_lds16(const bf16* g, bf16* l) {
    __builtin_amdgcn_global_load_lds(
        (const __attribute__((address_space(1))) void*)g,
        (__attribute__((address_space(3))) void*)l, 16, 0, 0);
}

// ---------------------------------------------------------------------------
// Small-tensor prep: b1_all = [sb1 | b1_0 | b1_1] (fp32), relu_b1 (bf16, the
// constant hidden rows of unrouted experts), bias_out = sb2 + b2_0 + b2_1.
// ---------------------------------------------------------------------------
__global__ void prep_small(const float* __restrict__ sb1, const float* __restrict__ b1,
                           const float* __restrict__ sb2, const float* __restrict__ b2,
                           float* __restrict__ b1_all, bf16* __restrict__ relu_b1,
                           float* __restrict__ bias_out)
{
    int i = blockIdx.x * 256 + threadIdx.x;   // 0..12287
    if (i < HIDDEN) {
        b1_all[i] = sb1[i];
    } else {
        float v = b1[i - HIDDEN];
        b1_all[i] = v;
        relu_b1[i - HIDDEN] = __float2bfloat16(v > 0.f ? v : 0.f);
    }
    if (i < D_MODEL) bias_out[i] = sb2[i] + b2[i] + b2[D_MODEL + i];
}

// ---------------------------------------------------------------------------
// 32x32 tiled transpose + fp32->bf16 cast:  dst[c][r] = (bf16)src[r][c]
// src: [R, Cc] fp32 contiguous.  dst: leading dim ldDst (bf16).
// ---------------------------------------------------------------------------
__global__ void transpose_cast(const float* __restrict__ src, bf16* __restrict__ dst,
                               int R, int Cc, int ldDst)
{
    __shared__ float tile[32][33];
    const int bx = blockIdx.x * 32;           // col base in src
    const int by = blockIdx.y * 32;           // row base in src
    const int tx = threadIdx.x & 31;
    const int ty = threadIdx.x >> 5;          // 0..7
#pragma unroll
    for (int i = 0; i < 32; i += 8)
        tile[ty + i][tx] = src[(size_t)(by + ty + i) * Cc + bx + tx];
    __syncthreads();
#pragma unroll
    for (int i = 0; i < 32; i += 8)
        dst[(size_t)(bx + ty + i) * ldDst + by + tx] = __float2bfloat16(tile[tx][ty + i]);
}

// ---------------------------------------------------------------------------
// Gating (fp32 dot, softmax-monotonic -> argmax) + x cast to bf16.
// One wave per token.
// ---------------------------------------------------------------------------
__global__ void gate_route_cast(const float* __restrict__ x, const float* __restrict__ gw,
                                int* __restrict__ route, bf16* __restrict__ Xb)
{
    const int token = blockIdx.x * 4 + (threadIdx.x >> 6);
    const int lane  = threadIdx.x & 63;
    const float4* xr = (const float4*)(x + (size_t)token * D_MODEL);
    const float4* g0 = (const float4*)gw;
    const float4* g1 = (const float4*)(gw + D_MODEL);
    bf16x4* xo = (bf16x4*)(Xb + (size_t)token * D_MODEL);
    float s0 = 0.f, s1 = 0.f;
    for (int i = lane; i < D_MODEL / 4; i += 64) {
        float4 v = xr[i];
        float4 a = g0[i], b = g1[i];
        s0 += v.x * a.x + v.y * a.y + v.z * a.z + v.w * a.w;
        s1 += v.x * b.x + v.y * b.y + v.z * b.z + v.w * b.w;
        bf16x4 o = { __float2bfloat16(v.x), __float2bfloat16(v.y),
                     __float2bfloat16(v.z), __float2bfloat16(v.w) };
        xo[i] = o;
    }
#pragma unroll
    for (int off = 32; off > 0; off >>= 1) {
        s0 += __shfl_down(s0, off, 64);
        s1 += __shfl_down(s1, off, 64);
    }
    if (lane == 0) route[token] = (s1 > s0) ? 1 : 0;   // argmax, first-index on tie
}

// ---------------------------------------------------------------------------
// Overwrite the UNROUTED expert's hidden block with relu(b1[e])  (bias leak).
// One block per token (within chunk).
// ---------------------------------------------------------------------------
__global__ void fix_unrouted(bf16* __restrict__ H, const int* __restrict__ route,
                             const bf16* __restrict__ relu_b1, int tok0)
{
    const int t = blockIdx.x;
    const int e = 1 - route[tok0 + t];
    float4* dst = (float4*)(H + (size_t)t * HP + HIDDEN + (size_t)e * HIDDEN);
    const float4* src = (const float4*)(relu_b1 + (size_t)e * HIDDEN);
    for (int i = threadIdx.x; i < HIDDEN / 8; i += 256) dst[i] = src[i];
}

// ---------------------------------------------------------------------------
// m97-style bf16 GEMM:  C[M,N] = A[M,K] @ B[N,K]^T  (+bias[col], EPI epilogue)
// 128x128 tile, 256 threads (4 waves, 2x2), 4x4 of mfma_f32_16x16x32_bf16,
// BK=32, global_load_lds width-16 staging.
// EPI==0: C bf16, v = relu(acc + bias).   EPI==1: C fp32, v = acc + bias.
// M,N multiples of 128; K multiple of 32.
// ---------------------------------------------------------------------------
template <int EPI>
__global__ __launch_bounds__(256, 2) void gemm_bt(
    const bf16* __restrict__ A, const bf16* __restrict__ B,
    void* __restrict__ Cout, const float* __restrict__ bias,
    int M, int N, int K)
{
    __shared__ bf16 lA[128 * 32];
    __shared__ bf16 lB[128 * 32];
    const int tid  = threadIdx.x;
    const int lane = tid & 63;
    const int wave = tid >> 6;
    const long bm = (long)blockIdx.y * 128;
    const long bn = (long)blockIdx.x * 128;

    // staging: 8 chunks of 16 rows each per operand; wave handles {wave, wave+4}
    const int sr0 = wave * 16 + (lane >> 2);
    const int sr1 = (wave + 4) * 16 + (lane >> 2);
    const int sc  = (lane & 3) * 8;                  // 8 bf16 = 16B per lane
    const bf16* Ag0 = A + (bm + sr0) * (long)K + sc;
    const bf16* Ag1 = A + (bm + sr1) * (long)K + sc;
    const bf16* Bg0 = B + (bn + sr0) * (long)K + sc;
    const bf16* Bg1 = B + (bn + sr1) * (long)K + sc;
    bf16* lA0 = &lA[wave * 512];
    bf16* lA1 = &lA[(wave + 4) * 512];
    bf16* lB0 = &lB[wave * 512];
    bf16* lB1 = &lB[(wave + 4) * 512];

    const int wr = (wave >> 1) * 64;   // wave's row quadrant
    const int wc = (wave & 1) * 64;    // wave's col quadrant
    const int fr = lane & 15;          // A row / B col within 16-tile
    const int fk = (lane >> 4) * 8;    // k offset within BK=32

    floatx4 acc[4][4];
#pragma unroll
    for (int i = 0; i < 4; i++)
#pragma unroll
        for (int j = 0; j < 4; j++) acc[i][j] = (floatx4){0.f, 0.f, 0.f, 0.f};

    for (int kt = 0; kt < K; kt += 32) {
        gload_lds16(Ag0, lA0);
        gload_lds16(Ag1, lA1);
        gload_lds16(Bg0, lB0);
        gload_lds16(Bg1, lB1);
        Ag0 += 32; Ag1 += 32; Bg0 += 32; Bg1 += 32;
        __syncthreads();   // drains vmcnt: staged tile visible
        short8 af[4], bf[4];
#pragma unroll
        for (int i = 0; i < 4; i++) {
            af[i] = *(const short8*)&lA[(wr + i * 16 + fr) * 32 + fk];
            bf[i] = *(const short8*)&lB[(wc + i * 16 + fr) * 32 + fk];
        }
#pragma unroll
        for (int i = 0; i < 4; i++)
#pragma unroll
            for (int j = 0; j < 4; j++)
                acc[i][j] = __builtin_amdgcn_mfma_f32_16x16x32_bf16(af[i], bf[j], acc[i][j], 0, 0, 0);
        __syncthreads();   // protect LDS before next staging overwrite
    }

    // epilogue: C/D layout col = lane&15, row = (lane>>4)*4 + reg
    const int rq = (lane >> 4) * 4;
#pragma unroll
    for (int j = 0; j < 4; j++) {
        const long col = bn + wc + j * 16 + fr;
        const float bv = bias[col];
#pragma unroll
        for (int i = 0; i < 4; i++) {
#pragma unroll
            for (int r = 0; r < 4; r++) {
                const long row = bm + wr + i * 16 + rq + r;
                float v = acc[i][j][r] + bv;
                if (EPI == 0) {
                    v = v > 0.f ? v : 0.f;
                    ((bf16*)Cout)[row * (long)N + col] = __float2bfloat16(v);
                } else {
                    ((float*)Cout)[row * (long)N + col] = v;
                }
            }
        }
    }
}

// ---------------------------------------------------------------------------
extern "C" void kernel_launch(void* const* d_in, const int* in_sizes, int n_in,
                              void* d_out, int out_size, void* d_ws, size_t ws_size,
                              hipStream_t stream)
{
    const float* x   = (const float*)d_in[0];
    const float* gw  = (const float*)d_in[1];
    const float* w1  = (const float*)d_in[2];   // [2, 1024, 4096]
    const float* b1  = (const float*)d_in[3];   // [2, 4096]
    const float* w2  = (const float*)d_in[4];   // [2, 4096, 1024]
    const float* b2  = (const float*)d_in[5];   // [2, 1024]
    const float* sw1 = (const float*)d_in[6];   // [1024, 4096]
    const float* sb1 = (const float*)d_in[7];
    const float* sw2 = (const float*)d_in[8];   // [4096, 1024]
    const float* sb2 = (const float*)d_in[9];
    float* out = (float*)d_out;

    // ---- workspace carve-up, adaptive to ws_size -------------------------
    // fixed: Xb 32MB + W1t 24MB + W2t 24MB + route/biases ~0.13MB ≈ 80.2 MB
    char* p = (char*)d_ws;
    bf16* Xb       = (bf16*)p;  p += (size_t)NTOK * D_MODEL * 2;   // 32 MB
    bf16* W1t      = (bf16*)p;  p += (size_t)HP * D_MODEL * 2;     // 24 MB  [HP, D] K-major
    bf16* W2t      = (bf16*)p;  p += (size_t)D_MODEL * HP * 2;     // 24 MB  [D, HP] K-major
    int*  route    = (int*)p;   p += (size_t)NTOK * 4;
    float* b1_all  = (float*)p; p += (size_t)HP * 4;
    bf16* relu_b1  = (bf16*)p;  p += (size_t)2 * HIDDEN * 2;
    float* bias_out= (float*)p; p += (size_t)D_MODEL * 4;
    bf16* H        = (bf16*)p;                                      // rest

    const size_t used_fixed = (size_t)(p - (char*)d_ws);
    const size_t avail = (ws_size > used_fixed) ? (ws_size - used_fixed) : 0;
    long chunk = (long)(avail / ((size_t)HP * 2));   // tokens that fit in H
    chunk = (chunk / 128) * 128;
    if (chunk > NTOK) chunk = NTOK;
    if (chunk < 128) chunk = 128;                    // last resort; needs 3 MB

    prep_small<<<HP / 256, 256, 0, stream>>>(sb1, b1, sb2, b2, b1_all, relu_b1, bias_out);

    // W1t rows h: [0,4096)=shared, [4096,8192)=e0, [8192,12288)=e1
    transpose_cast<<<dim3(HIDDEN / 32, D_MODEL / 32), 256, 0, stream>>>(
        sw1, W1t, D_MODEL, HIDDEN, D_MODEL);
    transpose_cast<<<dim3(HIDDEN / 32, D_MODEL / 32), 256, 0, stream>>>(
        w1, W1t + (size_t)HIDDEN * D_MODEL, D_MODEL, HIDDEN, D_MODEL);
    transpose_cast<<<dim3(HIDDEN / 32, D_MODEL / 32), 256, 0, stream>>>(
        w1 + (size_t)D_MODEL * HIDDEN, W1t + (size_t)2 * HIDDEN * D_MODEL, D_MODEL, HIDDEN, D_MODEL);
    // W2t[d][h]: columns h in same section order
    transpose_cast<<<dim3(D_MODEL / 32, HIDDEN / 32), 256, 0, stream>>>(
        sw2, W2t, HIDDEN, D_MODEL, HP);
    transpose_cast<<<dim3(D_MODEL / 32, HIDDEN / 32), 256, 0, stream>>>(
        w2, W2t + HIDDEN, HIDDEN, D_MODEL, HP);
    transpose_cast<<<dim3(D_MODEL / 32, HIDDEN / 32), 256, 0, stream>>>(
        w2 + (size_t)HIDDEN * D_MODEL, W2t + (size_t)2 * HIDDEN, HIDDEN, D_MODEL, HP);

    gate_route_cast<<<NTOK / 4, 256, 0, stream>>>(x, gw, route, Xb);

    for (long t0 = 0; t0 < NTOK; t0 += chunk) {
        const long cur = (NTOK - t0 < chunk) ? (NTOK - t0) : chunk;   // multiple of 128
        const bf16* Xc = Xb + t0 * D_MODEL;
        gemm_bt<0><<<dim3(HP / 128, cur / 128), 256, 0, stream>>>(
            Xc, W1t, H, b1_all, (int)cur, HP, D_MODEL);
        fix_unrouted<<<(int)cur, 256, 0, stream>>>(H, route, relu_b1, (int)t0);
        gemm_bt<1><<<dim3(D_MODEL / 128, cur / 128), 256, 0, stream>>>(
            H, W2t, out + t0 * D_MODEL, bias_out, (int)cur, D_MODEL, HP);
    }
}

// Round 3
// 1366.725 us; speedup vs baseline: 1.2506x; 1.2506x over previous
//
#include <hip/hip_runtime.h>
#include <hip/hip_bf16.h>

#define D_MODEL 1024
#define HIDDEN  4096
#define NTOK    16384
#define HP      12288   // shared + expert0 + expert1 hidden rows in W1t / cols in W2t
#define GPAD    16640   // 130 * 128 padded grouped-token space

typedef __hip_bfloat16 bf16;
typedef __attribute__((ext_vector_type(8))) short short8;
typedef __attribute__((ext_vector_type(4))) float floatx4;

struct bf16x4 { bf16 a, b, c, d; };

__device__ inline void gload_lds16(const bf16* g, bf16* l) {
    __builtin_amdgcn_global_load_lds(
        (const __attribute__((address_space(1))) void*)g,
        (__attribute__((address_space(3))) void*)l, 16, 0, 0);
}

// ---------------------------------------------------------------------------
// prep: b1_all = [sb1 | b1_0 | b1_1] (fp32); addvec[e] init = b2_0 + b2_1;
// cnt = 0.
// ---------------------------------------------------------------------------
__global__ void prep_small(const float* __restrict__ sb1, const float* __restrict__ b1,
                           const float* __restrict__ b2,
                           float* __restrict__ b1_all, float* __restrict__ addvec,
                           int* __restrict__ cnt)
{
    int i = blockIdx.x * 256 + threadIdx.x;   // 0..12287
    b1_all[i] = (i < HIDDEN) ? sb1[i] : b1[i - HIDDEN];
    if (i < D_MODEL) {
        float s = b2[i] + b2[D_MODEL + i];
        addvec[i] = s;
        addvec[D_MODEL + i] = s;
    }
    if (i < 2) cnt[i] = 0;
}

// ---------------------------------------------------------------------------
// addvec[1-e][d] += sum_h relu(b1[e][h]) * w2[e][h][d]   (the constant output
// of an unrouted expert, minus biases which prep_small already added).
// grid: 128 blocks = e(2) x hseg(16) x dblk(4); 256 threads = d in dblk.
// ---------------------------------------------------------------------------
__global__ void addvec_accum(const float* __restrict__ b1, const float* __restrict__ w2,
                             float* __restrict__ addvec)
{
    const int blk  = blockIdx.x;
    const int e    = blk >> 6;
    const int hseg = (blk >> 2) & 15;
    const int d    = (blk & 3) * 256 + threadIdx.x;
    const float* B1 = b1 + e * HIDDEN + hseg * 256;
    const float* W  = w2 + (size_t)e * HIDDEN * D_MODEL + (size_t)hseg * 256 * D_MODEL + d;
    float s = 0.f;
    for (int h = 0; h < 256; ++h) {
        float b = B1[h]; b = b > 0.f ? b : 0.f;
        s += b * W[(size_t)h * D_MODEL];
    }
    atomicAdd(&addvec[(1 - e) * D_MODEL + d], s);
}

// ---------------------------------------------------------------------------
// 32x32 tiled transpose + fp32->bf16 cast:  dst[c][r] = (bf16)src[r][c]
// ---------------------------------------------------------------------------
__global__ void transpose_cast(const float* __restrict__ src, bf16* __restrict__ dst,
                               int R, int Cc, int ldDst)
{
    __shared__ float tile[32][33];
    const int bx = blockIdx.x * 32;
    const int by = blockIdx.y * 32;
    const int tx = threadIdx.x & 31;
    const int ty = threadIdx.x >> 5;
#pragma unroll
    for (int i = 0; i < 32; i += 8)
        tile[ty + i][tx] = src[(size_t)(by + ty + i) * Cc + bx + tx];
    __syncthreads();
#pragma unroll
    for (int i = 0; i < 32; i += 8)
        dst[(size_t)(bx + ty + i) * ldDst + by + tx] = __float2bfloat16(tile[tx][ty + i]);
}

// ---------------------------------------------------------------------------
// Gating (fp32, argmax == softmax-top1) + x cast to bf16 + group position.
// One wave per token.
// ---------------------------------------------------------------------------
__global__ void gate_route_cast(const float* __restrict__ x, const float* __restrict__ gw,
                                int* __restrict__ route, int* __restrict__ pos,
                                int* __restrict__ cnt, bf16* __restrict__ Xb)
{
    const int token = blockIdx.x * 4 + (threadIdx.x >> 6);
    const int lane  = threadIdx.x & 63;
    const float4* xr = (const float4*)(x + (size_t)token * D_MODEL);
    const float4* g0 = (const float4*)gw;
    const float4* g1 = (const float4*)(gw + D_MODEL);
    bf16x4* xo = (bf16x4*)(Xb + (size_t)token * D_MODEL);
    float s0 = 0.f, s1 = 0.f;
    for (int i = lane; i < D_MODEL / 4; i += 64) {
        float4 v = xr[i];
        float4 a = g0[i], b = g1[i];
        s0 += v.x * a.x + v.y * a.y + v.z * a.z + v.w * a.w;
        s1 += v.x * b.x + v.y * b.y + v.z * b.z + v.w * b.w;
        bf16x4 o = { __float2bfloat16(v.x), __float2bfloat16(v.y),
                     __float2bfloat16(v.z), __float2bfloat16(v.w) };
        xo[i] = o;
    }
#pragma unroll
    for (int off = 32; off > 0; off >>= 1) {
        s0 += __shfl_down(s0, off, 64);
        s1 += __shfl_down(s1, off, 64);
    }
    if (lane == 0) {
        int r = (s1 > s0) ? 1 : 0;            // argmax, first-index on tie
        route[token] = r;
        pos[token] = atomicAdd(&cnt[r], 1);
    }
}

// gperm init + per-128-block expert id.  off1 = ceil(count0/128)*128.
__global__ void k_init(const int* __restrict__ cnt, int* __restrict__ gperm,
                       int* __restrict__ blkexp)
{
    int i = blockIdx.x * 256 + threadIdx.x;   // 0..GPAD-1
    int off1 = ((cnt[0] + 127) >> 7) << 7;
    if (i < GPAD) gperm[i] = -1;
    if (i < GPAD / 128) blkexp[i] = (i * 128 >= off1) ? 1 : 0;
}

__global__ void k_scatter(const int* __restrict__ route, const int* __restrict__ pos,
                          const int* __restrict__ cnt, int* __restrict__ gperm)
{
    int t = blockIdx.x * 256 + threadIdx.x;   // 0..NTOK-1
    int off1 = ((cnt[0] + 127) >> 7) << 7;
    int g = route[t] ? off1 + pos[t] : pos[t];
    gperm[g] = t;
}

// Xg[g] = Xb[gperm[g]] or 0.  2 rows per block, 128 threads/row, float4.
__global__ void gather_xg(const bf16* __restrict__ Xb, const int* __restrict__ gperm,
                          bf16* __restrict__ Xg)
{
    const int g = blockIdx.x * 2 + (threadIdx.x >> 7);
    const int l = threadIdx.x & 127;
    const int t = gperm[g];
    float4* dst = (float4*)(Xg + (size_t)g * D_MODEL);
    if (t >= 0) {
        const float4* src = (const float4*)(Xb + (size_t)t * D_MODEL);
        dst[l] = src[l];
    } else {
        dst[l] = make_float4(0.f, 0.f, 0.f, 0.f);
    }
}

// ---------------------------------------------------------------------------
// m97-style bf16 GEMM:  C[M,N] = A[M,K] @ B[N,K]^T (row stride ldb)
// 128x128 tile, 4 waves 2x2, 4x4 mfma_f32_16x16x32_bf16, BK=32, lds16 staging.
// MODE 0: shared GEMM1 -> H:   bf16 relu(acc + bias[col])
// MODE 1: shared GEMM2 -> out: fp32 acc + bias[col]
// MODE 2: grouped GEMM1 -> H:  expert e=blkexp[by]; B,bias offset by section
// MODE 3: grouped GEMM2:       scatter out[gperm[row]] += acc + addvec[e][col]
// ---------------------------------------------------------------------------
template <int MODE>
__global__ __launch_bounds__(256, 2) void gemm_bt(
    const bf16* __restrict__ A, const bf16* __restrict__ B,
    void* __restrict__ Cout, const float* __restrict__ bias,
    const int* __restrict__ blkexp, const int* __restrict__ gperm,
    int M, int N, int K, int ldb)
{
    __shared__ bf16 lA[128 * 32];
    __shared__ bf16 lB[128 * 32];
    const int tid  = threadIdx.x;
    const int lane = tid & 63;
    const int wave = tid >> 6;
    const long bm = (long)blockIdx.y * 128;
    const long bn = (long)blockIdx.x * 128;

    long bOff = 0;
    const float* biasP = bias;
    int e = 0;
    if (MODE == 2) {
        e = blkexp[blockIdx.y];
        bOff = (long)(1 + e) * HIDDEN * ldb;    // W1t expert row section
        biasP = bias + (1 + e) * HIDDEN;
    }
    if (MODE == 3) {
        e = blkexp[blockIdx.y];
        bOff = (long)(1 + e) * HIDDEN;          // W2t expert col section
        biasP = bias + e * D_MODEL;
    }

    const int sr0 = wave * 16 + (lane >> 2);
    const int sr1 = (wave + 4) * 16 + (lane >> 2);
    const int sc  = (lane & 3) * 8;
    const bf16* Ag0 = A + (bm + sr0) * (long)K + sc;
    const bf16* Ag1 = A + (bm + sr1) * (long)K + sc;
    const bf16* Bg0 = B + bOff + (bn + sr0) * (long)ldb + sc;
    const bf16* Bg1 = B + bOff + (bn + sr1) * (long)ldb + sc;
    bf16* lA0 = &lA[wave * 512];
    bf16* lA1 = &lA[(wave + 4) * 512];
    bf16* lB0 = &lB[wave * 512];
    bf16* lB1 = &lB[(wave + 4) * 512];

    const int wr = (wave >> 1) * 64;
    const int wc = (wave & 1) * 64;
    const int fr = lane & 15;
    const int fk = (lane >> 4) * 8;

    floatx4 acc[4][4];
#pragma unroll
    for (int i = 0; i < 4; i++)
#pragma unroll
        for (int j = 0; j < 4; j++) acc[i][j] = (floatx4){0.f, 0.f, 0.f, 0.f};

    for (int kt = 0; kt < K; kt += 32) {
        gload_lds16(Ag0, lA0);
        gload_lds16(Ag1, lA1);
        gload_lds16(Bg0, lB0);
        gload_lds16(Bg1, lB1);
        Ag0 += 32; Ag1 += 32; Bg0 += 32; Bg1 += 32;
        __syncthreads();
        short8 af[4], bf[4];
#pragma unroll
        for (int i = 0; i < 4; i++) {
            af[i] = *(const short8*)&lA[(wr + i * 16 + fr) * 32 + fk];
            bf[i] = *(const short8*)&lB[(wc + i * 16 + fr) * 32 + fk];
        }
#pragma unroll
        for (int i = 0; i < 4; i++)
#pragma unroll
            for (int j = 0; j < 4; j++)
                acc[i][j] = __builtin_amdgcn_mfma_f32_16x16x32_bf16(af[i], bf[j], acc[i][j], 0, 0, 0);
        __syncthreads();
    }

    // epilogue: C/D layout col = lane&15, row = (lane>>4)*4 + reg
    const int rq = (lane >> 4) * 4;
    int trow[16];
    if (MODE == 3) {
#pragma unroll
        for (int i = 0; i < 4; i++)
#pragma unroll
            for (int r = 0; r < 4; r++)
                trow[i * 4 + r] = gperm[bm + wr + i * 16 + rq + r];
    }
#pragma unroll
    for (int j = 0; j < 4; j++) {
        const long col = bn + wc + j * 16 + fr;
        const float bv = biasP[col];
#pragma unroll
        for (int i = 0; i < 4; i++) {
#pragma unroll
            for (int r = 0; r < 4; r++) {
                const long row = bm + wr + i * 16 + rq + r;
                float v = acc[i][j][r] + bv;
                if (MODE == 0 || MODE == 2) {
                    v = v > 0.f ? v : 0.f;
                    ((bf16*)Cout)[row * (long)N + col] = __float2bfloat16(v);
                } else if (MODE == 1) {
                    ((float*)Cout)[row * (long)N + col] = v;
                } else {   // MODE 3: scatter-add
                    int t = trow[i * 4 + r];
                    if (t >= 0) {
                        float* o = (float*)Cout + (size_t)t * D_MODEL + col;
                        *o += v;
                    }
                }
            }
        }
    }
}

// ---------------------------------------------------------------------------
extern "C" void kernel_launch(void* const* d_in, const int* in_sizes, int n_in,
                              void* d_out, int out_size, void* d_ws, size_t ws_size,
                              hipStream_t stream)
{
    const float* x   = (const float*)d_in[0];
    const float* gw  = (const float*)d_in[1];
    const float* w1  = (const float*)d_in[2];   // [2, 1024, 4096]
    const float* b1  = (const float*)d_in[3];   // [2, 4096]
    const float* w2  = (const float*)d_in[4];   // [2, 4096, 1024]
    const float* b2  = (const float*)d_in[5];   // [2, 1024]
    const float* sw1 = (const float*)d_in[6];   // [1024, 4096]
    const float* sb1 = (const float*)d_in[7];
    const float* sw2 = (const float*)d_in[8];   // [4096, 1024]
    const float* sb2 = (const float*)d_in[9];
    float* out = (float*)d_out;

    // ---- workspace carve-up (fixed ~114.5 MB + H) ------------------------
    char* p = (char*)d_ws;
    bf16* Xb      = (bf16*)p;  p += (size_t)NTOK * D_MODEL * 2;    // 32 MB
    bf16* Xg      = (bf16*)p;  p += (size_t)GPAD * D_MODEL * 2;    // 32.5 MB
    bf16* W1t     = (bf16*)p;  p += (size_t)HP * D_MODEL * 2;      // 24 MB  [HP,1024]
    bf16* W2t     = (bf16*)p;  p += (size_t)D_MODEL * HP * 2;      // 24 MB  [1024,HP]
    int*  route   = (int*)p;   p += (size_t)NTOK * 4;
    int*  pos     = (int*)p;   p += (size_t)NTOK * 4;
    int*  gperm   = (int*)p;   p += (size_t)GPAD * 4;
    int*  blkexp  = (int*)p;   p += (size_t)(GPAD / 128) * 4;
    int*  cnt     = (int*)p;   p += 2 * 4;
    float* b1_all = (float*)p; p += (size_t)HP * 4;
    float* addvec = (float*)p; p += (size_t)2 * D_MODEL * 4;
    bf16* H       = (bf16*)p;                                      // rest

    const size_t used_fixed = (size_t)(p - (char*)d_ws);
    const size_t avail = (ws_size > used_fixed) ? (ws_size - used_fixed) : 0;
    long cs = (long)(avail / ((size_t)HIDDEN * 2));   // tokens per H chunk
    cs = (cs / 128) * 128;
    if (cs > GPAD) cs = GPAD;
    if (cs < 128) cs = 128;

    prep_small<<<HP / 256, 256, 0, stream>>>(sb1, b1, b2, b1_all, addvec, cnt);
    addvec_accum<<<128, 256, 0, stream>>>(b1, w2, addvec);

    // W1t rows h: [0,4096)=shared, [4096,8192)=e0, [8192,12288)=e1 ; ld 1024
    transpose_cast<<<dim3(HIDDEN / 32, D_MODEL / 32), 256, 0, stream>>>(
        sw1, W1t, D_MODEL, HIDDEN, D_MODEL);
    transpose_cast<<<dim3(HIDDEN / 32, D_MODEL / 32), 256, 0, stream>>>(
        w1, W1t + (size_t)HIDDEN * D_MODEL, D_MODEL, HIDDEN, D_MODEL);
    transpose_cast<<<dim3(HIDDEN / 32, D_MODEL / 32), 256, 0, stream>>>(
        w1 + (size_t)D_MODEL * HIDDEN, W1t + (size_t)2 * HIDDEN * D_MODEL, D_MODEL, HIDDEN, D_MODEL);
    // W2t [1024 rows, ld HP]: cols [0,4096)=shared, then e0, e1
    transpose_cast<<<dim3(D_MODEL / 32, HIDDEN / 32), 256, 0, stream>>>(
        sw2, W2t, HIDDEN, D_MODEL, HP);
    transpose_cast<<<dim3(D_MODEL / 32, HIDDEN / 32), 256, 0, stream>>>(
        w2, W2t + HIDDEN, HIDDEN, D_MODEL, HP);
    transpose_cast<<<dim3(D_MODEL / 32, HIDDEN / 32), 256, 0, stream>>>(
        w2 + (size_t)HIDDEN * D_MODEL, W2t + (size_t)2 * HIDDEN, HIDDEN, D_MODEL, HP);

    gate_route_cast<<<NTOK / 4, 256, 0, stream>>>(x, gw, route, pos, cnt, Xb);
    k_init<<<(GPAD + 255) / 256, 256, 0, stream>>>(cnt, gperm, blkexp);
    k_scatter<<<NTOK / 256, 256, 0, stream>>>(route, pos, cnt, gperm);
    gather_xg<<<GPAD / 2, 256, 0, stream>>>(Xb, gperm, Xg);

    // ---- shared FFN over all tokens (writes out = shared + sb2) ----------
    for (long t0 = 0; t0 < NTOK; t0 += cs) {
        const long cur = (NTOK - t0 < cs) ? (NTOK - t0) : cs;
        gemm_bt<0><<<dim3(HIDDEN / 128, cur / 128), 256, 0, stream>>>(
            Xb + t0 * D_MODEL, W1t, H, b1_all, nullptr, nullptr,
            (int)cur, HIDDEN, D_MODEL, D_MODEL);
        gemm_bt<1><<<dim3(D_MODEL / 128, cur / 128), 256, 0, stream>>>(
            H, W2t, out + t0 * D_MODEL, sb2, nullptr, nullptr,
            (int)cur, D_MODEL, HIDDEN, HP);
    }
    // ---- routed expert over grouped tokens (scatter-add) -----------------
    for (long g0 = 0; g0 < GPAD; g0 += cs) {
        const long cur = (GPAD - g0 < cs) ? (GPAD - g0) : cs;
        gemm_bt<2><<<dim3(HIDDEN / 128, cur / 128), 256, 0, stream>>>(
            Xg + g0 * D_MODEL, W1t, H, b1_all, blkexp + g0 / 128, nullptr,
            (int)cur, HIDDEN, D_MODEL, D_MODEL);
        gemm_bt<3><<<dim3(D_MODEL / 128, cur / 128), 256, 0, stream>>>(
            H, W2t, (void*)out, addvec, blkexp + g0 / 128, gperm + g0,
            (int)cur, D_MODEL, HIDDEN, HP);
    }
}